// Round 21
// baseline (56.566 us; speedup 1.0000x reference)
//
#include <hip/hip_runtime.h>
#include <hip/hip_bf16.h>
#include <math.h>

#define N_PTS 8192
#define D_FEAT 64
#define TPB 1024               // 16 waves
#define ROWS_B 32              // i-rows per block
#define PASSES 16              // 256 chunks / 16 waves
#define CAP 512                // survivor capacity per row
// LDS float offsets
#define NORM_OFF 0             // 8192 norms
#define MIN_OFF  8192          // 32 rows x 32 lane-minima
#define TAU_OFF  9216          // 32 taus
#define SV_OFF   9248          // 32 x CAP survivors
#define LDS_F    (9248 + 32 * CAP)

typedef __attribute__((ext_vector_type(8))) short short8v;   // 8 bf16 = 4 VGPR
typedef __attribute__((ext_vector_type(16))) float f32x16;   // 32x32 MFMA acc

// Fragment-major hi-only layout: unit u (16B = 8 bf16 of K=64) of row r in
// chunk c lives at short-offset ((c*8 + u)*32 + (r&31)) * 8.
__device__ ushort g_X2[N_PTS * D_FEAT];   // 1 MB packed bf16
__device__ float  g_x2n[N_PTS];           // exact f32 squared norms
__device__ float  g_md[N_PTS];            // mean NN distance

// ---- pack: fp32 row -> bf16 (RNE), fragment-major + exact f32 norm ----
__global__ __launch_bounds__(256) void pack_kernel(const float* __restrict__ x) {
    const int row = blockIdx.x * 256 + threadIdx.x;
    const int chunk = row >> 5, r = row & 31;
    const float4* xr = (const float4*)(x + (size_t)row * D_FEAT);
    ushort* base = g_X2 + (size_t)chunk * 2048 + r * 8;
    float norm = 0.f;
    #pragma unroll
    for (int it = 0; it < 8; ++it) {
        float4 a = xr[2 * it], b = xr[2 * it + 1];
        float vals[8] = {a.x, a.y, a.z, a.w, b.x, b.y, b.z, b.w};
        uint hi[8];
        #pragma unroll
        for (int e = 0; e < 8; ++e) {
            float v = vals[e];
            norm += v * v;
            uint u = __float_as_uint(v);
            hi[e] = (u + 0x7fffu + ((u >> 16) & 1u)) >> 16;   // RNE bf16
        }
        *(uint4*)(base + it * 256) = make_uint4(
            hi[0] | (hi[1] << 16), hi[2] | (hi[3] << 16),
            hi[4] | (hi[5] << 16), hi[6] | (hi[7] << 16));
    }
    g_x2n[row] = norm;
}

// compare-exchange: ascending
#define CE(A, B) { float lo_ = fminf(A, B); float hi_ = fmaxf(A, B); A = lo_; B = hi_; }

// ---- main: two-phase exact threshold kNN ----
__global__ __launch_bounds__(TPB, 4) void nn_kernel() {
    __shared__ float s_mem[LDS_F];   // ~100 KB
    __shared__ int   s_cnt[32];
    const int t    = threadIdx.x;
    const int lane = t & 63;
    const int w    = t >> 6;       // wave 0..15
    const int il   = lane & 31;    // i-row within chunk (MFMA col)
    const int h    = lane >> 5;    // unit parity / j-subgroup
    const int ib   = blockIdx.x;   // i-chunk 0..255
    const int i0   = ib * ROWS_B;
    const float INF = __builtin_inff();

    // stage ALL norms into LDS; zero survivor counters
    {
        float4* s4 = (float4*)s_mem;
        const float4* g4 = (const float4*)g_x2n;
        #pragma unroll
        for (int q = 0; q < 2; ++q) s4[t + q * TPB] = g4[t + q * TPB];
        if (t < 32) s_cnt[t] = 0;
    }

    const short8v* Xf = (const short8v*)g_X2;

    // B-frag: block's 32 i-rows, K=64, persistent (16 regs)
    short8v bfr[4];
    {
        const short8v* bp = Xf + ((size_t)ib * 8 + h) * 32 + il;
        #pragma unroll
        for (int tt = 0; tt < 4; ++tt) bfr[tt] = bp[tt * 64];
    }
    __syncthreads();

    const short8v* abase = Xf + ((size_t)w * 8 + h) * 32 + il;
    #define ALOAD(dst, p) { \
        const short8v* ab_ = abase + (size_t)(p) * 4096; \
        _Pragma("unroll") \
        for (int tt = 0; tt < 4; ++tt) dst[tt] = ab_[tt * 64]; }

    #define MFMA4(accv, areg) { \
        _Pragma("unroll") \
        for (int r = 0; r < 16; ++r) accv[r] = 0.f; \
        _Pragma("unroll") \
        for (int tt = 0; tt < 4; ++tt) \
            accv = __builtin_amdgcn_mfma_f32_32x32x16_bf16(areg[tt], bfr[tt], accv, 0, 0, 0); }

    // ---- Loop 1: per-lane stream minimum (2 inst/candidate) ----
    float mmin = INF;
    #define EPILOG_MIN(accv, p) { \
        const int cl_ = (p) * 16 + w; \
        _Pragma("unroll") \
        for (int g = 0; g < 4; ++g) { \
            float4 xq = *(const float4*)&s_mem[cl_ * 32 + 8 * g + 4 * h]; \
            float cand[4] = {xq.x, xq.y, xq.z, xq.w}; \
            _Pragma("unroll") \
            for (int e = 0; e < 4; ++e) \
                mmin = fminf(mmin, fmaf(-2.f, accv[4 * g + e], cand[e])); \
        } }

    {
        short8v a0[4], a1[4];
        f32x16 acc;
        ALOAD(a0, 0);
        #pragma unroll 1
        for (int pp = 0; pp < PASSES / 2; ++pp) {
            const int p0 = 2 * pp, p1 = 2 * pp + 1;
            ALOAD(a1, p1);
            MFMA4(acc, a0);
            EPILOG_MIN(acc, p0);
            if (pp < PASSES / 2 - 1) ALOAD(a0, p0 + 2);
            MFMA4(acc, a1);
            EPILOG_MIN(acc, p1);
        }
    }
    s_mem[MIN_OFF + il * 32 + (w * 2 + h)] = mmin;
    __syncthreads();

    // ---- tau phase: per row, 17th smallest of 32 lane-minima ----
    // (valid upper bound on the 17th smallest key = self + 16 NN)
    {
        const int r2 = 2 * w + (lane >> 5);   // row 0..31
        const int idx = lane & 31;
        float m = s_mem[MIN_OFF + r2 * 32 + idx];
        #pragma unroll
        for (int k = 2; k <= 32; k <<= 1) {
            #pragma unroll
            for (int j = k >> 1; j > 0; j >>= 1) {
                float o = __shfl_xor(m, j);
                const bool low = ((idx & j) == 0);
                const bool up  = ((idx & k) == 0);
                float mn = fminf(m, o), mx = fmaxf(m, o);
                m = (low == up) ? mn : mx;
            }
        }
        if (idx == 16) s_mem[TAU_OFF + r2] = m;   // rank 16 (0-based) = 17th
    }
    __syncthreads();

    // ---- Loop 2: recompute + filter (appends are rare) ----
    const float mytau = s_mem[TAU_OFF + il];
    #define EPILOG_FLT(accv, p) { \
        const int cl_ = (p) * 16 + w; \
        _Pragma("unroll") \
        for (int g = 0; g < 4; ++g) { \
            float4 xq = *(const float4*)&s_mem[cl_ * 32 + 8 * g + 4 * h]; \
            float cand[4] = {xq.x, xq.y, xq.z, xq.w}; \
            _Pragma("unroll") \
            for (int e = 0; e < 4; ++e) { \
                float v = fmaf(-2.f, accv[4 * g + e], cand[e]); \
                if (v <= mytau) { \
                    int ix_ = atomicAdd(&s_cnt[il], 1); \
                    if (ix_ < CAP) s_mem[SV_OFF + il * CAP + ix_] = v; \
                } \
            } \
        } }

    {
        short8v a0[4], a1[4];
        f32x16 acc;
        ALOAD(a0, 0);
        #pragma unroll 1
        for (int pp = 0; pp < PASSES / 2; ++pp) {
            const int p0 = 2 * pp, p1 = 2 * pp + 1;
            ALOAD(a1, p1);
            MFMA4(acc, a0);
            EPILOG_FLT(acc, p0);
            if (pp < PASSES / 2 - 1) ALOAD(a0, p0 + 2);
            MFMA4(acc, a1);
            EPILOG_FLT(acc, p1);
        }
    }
    __syncthreads();

    // ---- extraction: per row, sort survivors, skip min (self), mean-16 ----
    {
        const int r2 = 2 * w + (lane >> 5);   // row 0..31
        const int sl = lane & 31;
        const int row = i0 + r2;
        int n = s_cnt[r2];
        if (n > CAP) n = CAP;
        float tl[16];
        #pragma unroll
        for (int q = 0; q < 16; ++q) {
            const int ix = sl + 32 * q;
            tl[q] = (ix < n) ? s_mem[SV_OFF + r2 * CAP + ix] : INF;
        }
        // Batcher merge-exchange sort-16 ascending (63 CE)
        CE(tl[0],tl[8]) CE(tl[1],tl[9]) CE(tl[2],tl[10]) CE(tl[3],tl[11])
        CE(tl[4],tl[12]) CE(tl[5],tl[13]) CE(tl[6],tl[14]) CE(tl[7],tl[15])
        CE(tl[0],tl[4]) CE(tl[1],tl[5]) CE(tl[2],tl[6]) CE(tl[3],tl[7])
        CE(tl[8],tl[12]) CE(tl[9],tl[13]) CE(tl[10],tl[14]) CE(tl[11],tl[15])
        CE(tl[4],tl[8]) CE(tl[5],tl[9]) CE(tl[6],tl[10]) CE(tl[7],tl[11])
        CE(tl[0],tl[2]) CE(tl[1],tl[3]) CE(tl[4],tl[6]) CE(tl[5],tl[7])
        CE(tl[8],tl[10]) CE(tl[9],tl[11]) CE(tl[12],tl[14]) CE(tl[13],tl[15])
        CE(tl[2],tl[8]) CE(tl[3],tl[9]) CE(tl[6],tl[12]) CE(tl[7],tl[13])
        CE(tl[2],tl[4]) CE(tl[3],tl[5]) CE(tl[6],tl[8]) CE(tl[7],tl[9])
        CE(tl[10],tl[12]) CE(tl[11],tl[13])
        CE(tl[0],tl[1]) CE(tl[2],tl[3]) CE(tl[4],tl[5]) CE(tl[6],tl[7])
        CE(tl[8],tl[9]) CE(tl[10],tl[11]) CE(tl[12],tl[13]) CE(tl[14],tl[15])
        CE(tl[1],tl[8]) CE(tl[3],tl[10]) CE(tl[5],tl[12]) CE(tl[7],tl[14])
        CE(tl[1],tl[4]) CE(tl[3],tl[6]) CE(tl[5],tl[8]) CE(tl[7],tl[10])
        CE(tl[9],tl[12]) CE(tl[11],tl[14])
        CE(tl[1],tl[2]) CE(tl[3],tl[4]) CE(tl[5],tl[6]) CE(tl[7],tl[8])
        CE(tl[9],tl[10]) CE(tl[11],tl[12]) CE(tl[13],tl[14])

        const float x2r = g_x2n[row];
        float sum = 0.f;
        #pragma unroll 1
        for (int it = 0; it < 17; ++it) {      // 17 extractions; skip #0 = self
            float m = tl[0]; int src = sl;
            #pragma unroll
            for (int off = 16; off > 0; off >>= 1) {   // within 32-lane group
                float om = __shfl_xor(m, off);
                int os = __shfl_xor(src, off);
                if (om < m || (om == m && os < src)) { m = om; src = os; }
            }
            if (it > 0) sum += sqrtf(fmaxf(m + x2r, 0.f));
            const bool pop = (sl == src);
            #pragma unroll
            for (int k = 0; k < 15; ++k) tl[k] = pop ? tl[k + 1] : tl[k];
            tl[15] = pop ? INF : tl[15];
        }
        if (sl == 0) g_md[row] = sum * (1.f / 16.f);
    }
}

// ---- scalar loss ----
__global__ __launch_bounds__(1024) void loss_kernel(float* __restrict__ out) {
    __shared__ float s[1024];
    const int t = threadIdx.x;

    float m = -__builtin_inff();
    for (int j = t; j < N_PTS; j += 1024) m = fmaxf(m, g_md[j]);
    s[t] = m; __syncthreads();
    for (int off = 512; off > 0; off >>= 1) {
        if (t < off) s[t] = fmaxf(s[t], s[t + off]);
        __syncthreads();
    }
    m = s[0]; __syncthreads();

    float se = 0.f, sm = 0.f;
    for (int j = t; j < N_PTS; j += 1024) {
        float v = g_md[j];
        se += expf(v - m);
        sm += v;
    }
    s[t] = se; __syncthreads();
    for (int off = 512; off > 0; off >>= 1) {
        if (t < off) s[t] += s[t + off];
        __syncthreads();
    }
    float S = s[0]; __syncthreads();
    s[t] = sm; __syncthreads();
    for (int off = 512; off > 0; off >>= 1) {
        if (t < off) s[t] += s[t + off];
        __syncthreads();
    }
    float M = s[0];

    if (t == 0) {
        const float n = (float)N_PTS;
        out[0] = -logf(n) - M / n + (m + logf(S));
    }
}

extern "C" void kernel_launch(void* const* d_in, const int* in_sizes, int n_in,
                              void* d_out, int out_size, void* d_ws, size_t ws_size,
                              hipStream_t stream) {
    const float* x = (const float*)d_in[0];
    float* out = (float*)d_out;

    pack_kernel<<<N_PTS / 256, 256, 0, stream>>>(x);
    nn_kernel<<<N_PTS / ROWS_B, TPB, 0, stream>>>();
    loss_kernel<<<1, 1024, 0, stream>>>(out);
}